// Round 7
// baseline (128995.630 us; speedup 1.0000x reference)
//
#include <hip/hip_runtime.h>
#include <cmath>

// ---------------------------------------------------------------------------
// LPCNet-style vocoder on MI355X — round 7: 4-chain interleave per CU-group.
// R5 measured 3.33us/step with the cross-CU LLC h-exchange round-trip (~1.5-2us)
// fully exposed on the serial AR critical path. R6 proved swizzle (conflicts
// 3e8->6e6) but serialized the epilogue on wave0 (-30%).
// R7: 2 groups x 8 CUs; each group runs FOUR batch chains interleaved.
// Weights (48 AGPR W_h-share + 128 pinned-VGPR full out_w) are shared across
// chains; per-chain state is small. A chain's h-post is consumed 3 stages
// (~2-3us of other chains' compute) later -> LLC RT fully hidden, polls hit
// on first read. Parallel finalize (256 thr) + LDS flag mini-sync; gates keep
// h_own in registers. Arithmetic identical to passing R5.
// ---------------------------------------------------------------------------

#define NB 8
#define NF 64
#define ND 20
#define NH 256
#define NG 768      // 3*NH
#define FS 160
#define NT (NF * FS)   // 10240

#define AGENT __HIP_MEMORY_SCOPE_AGENT
#define WG    __HIP_MEMORY_SCOPE_WORKGROUP
#define HLAY(c) ((((c) >> 4) * 20) + ((c) & 15))   // 16-float groups, 20-float stride

#define AG_W(dst, src) asm volatile("v_accvgpr_write_b32 %0, %1" : "=a"(dst) : "v"(src))
#define AG_R(dst, src) asm volatile("v_accvgpr_read_b32 %0, %1" : "=v"(dst) : "a"(src))
#define VPIN(dst, src) asm volatile("v_mov_b32 %0, %1" : "=v"(dst) : "v"(src))

// ---------------------------------------------------------------------------
// Kernel A: FrameRateNet + gi_cond precompute (unchanged, passing).
// ---------------------------------------------------------------------------
__global__ __launch_bounds__(128) void frn_kernel(
    const float* __restrict__ feat,
    const float* __restrict__ w1,
    const float* __restrict__ b1,
    const float* __restrict__ w2,
    const float* __restrict__ b2,
    const float* __restrict__ fw1,
    const float* __restrict__ fb1,
    const float* __restrict__ fw2,
    const float* __restrict__ fb2,
    const float* __restrict__ wi,
    const float* __restrict__ bi,
    float* __restrict__ gic)
{
    const int bf = blockIdx.x;
    const int b = bf >> 6;
    const int f = bf & 63;
    const int o = threadIdx.x;

    __shared__ float sfeat[5][ND];
    __shared__ float sc1[3][128];
    __shared__ float sc2[128];
    __shared__ float sc3[128];
    __shared__ float scond[128];

    for (int i = o; i < 5 * ND; i += 128) {
        int ff = f - 2 + i / ND;
        int c = i % ND;
        sfeat[i / ND][c] = (ff >= 0 && ff < NF) ? feat[((size_t)b * NF + ff) * ND + c] : 0.f;
    }
    __syncthreads();

    for (int df = 0; df < 3; ++df) {
        int fp = f - 1 + df;
        if (fp >= 0 && fp < NF) {
            float acc = b1[o];
            for (int k = 0; k < 3; ++k)
                for (int c = 0; c < ND; ++c)
                    acc += sfeat[df + k][c] * w1[(k * ND + c) * 128 + o];
            sc1[df][o] = tanhf(acc);
        } else {
            sc1[df][o] = 0.f;
        }
    }
    __syncthreads();

    {
        float acc = b2[o];
        for (int k = 0; k < 3; ++k)
            for (int c = 0; c < 128; ++c)
                acc += sc1[k][c] * w2[(k * 128 + c) * 128 + o];
        sc2[o] = tanhf(acc);
    }
    __syncthreads();
    {
        float acc = fb1[o];
        for (int c = 0; c < 128; ++c) acc += sc2[c] * fw1[c * 128 + o];
        sc3[o] = tanhf(acc);
    }
    __syncthreads();
    {
        float acc = fb2[o];
        for (int c = 0; c < 128; ++c) acc += sc3[c] * fw2[c * 128 + o];
        scond[o] = tanhf(acc);
    }
    __syncthreads();

    for (int r = 0; r < 6; ++r) {
        int j = o + 128 * r;
        float acc = bi[j];
        const float* wr = wi + (size_t)j * 129 + 1;
        for (int c = 0; c < 128; ++c) acc += scond[c] * wr[c];
        gic[(size_t)bf * NG + j] = acc;
    }
}

// ---------------------------------------------------------------------------
// Kernel B: AR loop. 16 blocks: group g = bid&1 (batches 4g..4g+3),
// CU index j = bid>>1 (0..7). 512 threads.
// ---------------------------------------------------------------------------
__global__ __launch_bounds__(512, 2) void ar_kernel(
    const float* __restrict__ gic,    // (8*64, 768)
    const float* __restrict__ wh,     // (768,256) fp32
    const float* __restrict__ ow,     // (256,256) [c][o] native
    const float* __restrict__ wi,     // (768,129) — need column 0
    const float* __restrict__ bh,     // (768,)
    const float* __restrict__ ob,     // (256,)
    float* __restrict__ wav_out,      // (8, 10240)
    float* __restrict__ logits_out,   // (8, 10240, 256)
    unsigned long long* __restrict__ hxp)  // [8][2][256] packed {tag,h}
{
    const int bid = blockIdx.x;
    const int g = bid & 1;            // group -> batches 4g..4g+3
    const int j = bid >> 1;           // CU index within group, 0..7
    const int t = threadIdx.x;
    const int qq = t >> 4;            // 0..31: local hidden unit (P1 rows)
    const int ss = t & 15;            // K-chunk of 16 cols (low 4 lane bits)
    const int og = t >> 3;            // 0..63: o-group of 4 (P3)
    const int c8 = t & 7;             // c-chunk of 32 (P3)
    const int gu32 = 32 * j;          // own row-block base

    __shared__ __align__(16) float hsp[4][16 * 20];  // h per chain, skewed
    __shared__ __align__(16) float pl[4][8][256];    // logits partials, swizzled
    __shared__ float ghfin[4][32][3];                // reduced gh rows per chain
    __shared__ float candv[4];
    __shared__ int   candi[4];
    __shared__ int   fc[4];                          // wave flags (global stage ctr)

    // ---- W_h share -> 48 AGPRs (shared across chains) ----
    float A0[16], A1[16], A2[16];
    {
        const float4* wb = (const float4*)wh;      // row = 64 float4
        size_t r0 = (size_t)(gu32 + qq) * 64 + ss * 4;
        #pragma unroll
        for (int i = 0; i < 4; ++i) {
            float4 x0 = wb[r0 + i];
            AG_W(A0[4*i+0], x0.x); AG_W(A0[4*i+1], x0.y);
            AG_W(A0[4*i+2], x0.z); AG_W(A0[4*i+3], x0.w);
        }
        #pragma unroll
        for (int i = 0; i < 4; ++i) {
            float4 x1 = wb[r0 + 256 * 64 + i];
            AG_W(A1[4*i+0], x1.x); AG_W(A1[4*i+1], x1.y);
            AG_W(A1[4*i+2], x1.z); AG_W(A1[4*i+3], x1.w);
        }
        #pragma unroll
        for (int i = 0; i < 4; ++i) {
            float4 x2 = wb[r0 + 512 * 64 + i];
            AG_W(A2[4*i+0], x2.x); AG_W(A2[4*i+1], x2.y);
            AG_W(A2[4*i+2], x2.z); AG_W(A2[4*i+3], x2.w);
        }
    }
    // ---- FULL out_w -> 128 pinned VGPRs (shared across chains) ----
    float4 OW4[32];
    {
        const float4* op = (const float4*)ow;      // row c = 64 float4
        #pragma unroll
        for (int i = 0; i < 32; ++i) {
            float4 x = op[(size_t)(c8 * 32 + i) * 64 + og];
            VPIN(OW4[i].x, x.x); VPIN(OW4[i].y, x.y);
            VPIN(OW4[i].z, x.z); VPIN(OW4[i].w, x.w);
        }
    }

    // ---- per-thread scalars (shared across chains) ----
    float bh_r = 0, bh_z = 0, bh_n = 0, wi_r = 0, wi_z = 0, wi_n = 0;
    if (t < 32) {
        int gr = gu32 + t;
        bh_r = bh[gr]; bh_z = bh[gr + 256]; bh_n = bh[gr + 512];
        wi_r = wi[(size_t)gr * 129];
        wi_z = wi[(size_t)(gr + 256) * 129];
        wi_n = wi[(size_t)(gr + 512) * 129];
    }
    float ob_o = (t < NH) ? ob[t] : 0.f;

    // ---- per-chain state ----
    float prevc[4] = {0, 0, 0, 0}, yaccc[4] = {0, 0, 0, 0};
    float hreg[4] = {0, 0, 0, 0};                       // own h unit (t<32)
    float gr_[4] = {0,0,0,0}, gz_[4] = {0,0,0,0}, gn_[4] = {0,0,0,0};
    #pragma unroll
    for (int c = 0; c < 4; ++c)
        if (t < NH) hsp[c][HLAY(t)] = 0.f;
    if (t < 4) fc[t] = 0;
    int fr = 0, sif = 0;
    __syncthreads();

    for (int n = 0; n <= NT; ++n) {
        // refresh gic caches once per frame (3 L2 loads per chain, amortized)
        if (sif == 0 && n < NT && t < 32) {
            #pragma unroll
            for (int c = 0; c < 4; ++c) {
                const float* gf = gic + ((size_t)(4 * g + c) * NF + fr) * NG;
                int guu = gu32 + t;
                gr_[c] = gf[guu]; gz_[c] = gf[guu + 256]; gn_[c] = gf[guu + 512];
            }
        }

        #pragma unroll
        for (int c = 0; c < 4; ++c) {
            const int bb = 4 * g + c;
            unsigned long long* hxb = hxp + (size_t)bb * 2 * 256;
            const int gsc = n * 4 + c + 1;   // global stage counter (monotonic)

            // ---- step1: P1 (gh partials) + P3 (logits partials) ----
            if (n < NT) {
                const float4* h4 = (const float4*)hsp[c];
                float a0 = 0.f, a1 = 0.f, a2 = 0.f;
                #pragma unroll
                for (int i = 0; i < 4; ++i) {
                    float4 hv = h4[ss * 5 + i];
                    float w;
                    AG_R(w, A0[4*i+0]); a0 += w * hv.x;
                    AG_R(w, A0[4*i+1]); a0 += w * hv.y;
                    AG_R(w, A0[4*i+2]); a0 += w * hv.z;
                    AG_R(w, A0[4*i+3]); a0 += w * hv.w;
                    AG_R(w, A1[4*i+0]); a1 += w * hv.x;
                    AG_R(w, A1[4*i+1]); a1 += w * hv.y;
                    AG_R(w, A1[4*i+2]); a1 += w * hv.z;
                    AG_R(w, A1[4*i+3]); a1 += w * hv.w;
                    AG_R(w, A2[4*i+0]); a2 += w * hv.x;
                    AG_R(w, A2[4*i+1]); a2 += w * hv.y;
                    AG_R(w, A2[4*i+2]); a2 += w * hv.z;
                    AG_R(w, A2[4*i+3]); a2 += w * hv.w;
                }
                #pragma unroll
                for (int d = 1; d <= 8; d <<= 1) {
                    a0 += __shfl_xor(a0, d);
                    a1 += __shfl_xor(a1, d);
                    a2 += __shfl_xor(a2, d);
                }
                if (ss == 0) {
                    ghfin[c][qq][0] = a0; ghfin[c][qq][1] = a1; ghfin[c][qq][2] = a2;
                }
            }
            if (n > 0) {
                const float4* h4 = (const float4*)hsp[c];
                float4 acc = {0.f, 0.f, 0.f, 0.f};
                #pragma unroll
                for (int i = 0; i < 8; ++i) {
                    float4 hv = h4[(c8 * 2 + (i >> 2)) * 5 + (i & 3)];
                    acc.x += hv.x * OW4[4*i+0].x; acc.y += hv.x * OW4[4*i+0].y;
                    acc.z += hv.x * OW4[4*i+0].z; acc.w += hv.x * OW4[4*i+0].w;
                    acc.x += hv.y * OW4[4*i+1].x; acc.y += hv.y * OW4[4*i+1].y;
                    acc.z += hv.y * OW4[4*i+1].z; acc.w += hv.y * OW4[4*i+1].w;
                    acc.x += hv.z * OW4[4*i+2].x; acc.y += hv.z * OW4[4*i+2].y;
                    acc.z += hv.z * OW4[4*i+2].z; acc.w += hv.z * OW4[4*i+2].w;
                    acc.x += hv.w * OW4[4*i+3].x; acc.y += hv.w * OW4[4*i+3].y;
                    acc.z += hv.w * OW4[4*i+3].z; acc.w += hv.w * OW4[4*i+3].w;
                }
                *(float4*)&pl[c][c8][(og ^ c8) << 2] = acc;   // swizzled: conflict-free
            }
            __syncthreads();   // b1

            // ---- step3: finalize+argmax (t<256)  ||  poll next chain (t in [256,480)) ----
            if (t < NH) {
                if (n > 0) {
                    float lg = ob_o;
                    int og0 = t >> 2, q = t & 3;
                    #pragma unroll
                    for (int ci = 0; ci < 8; ++ci)
                        lg += pl[c][ci][((og0 ^ ci) << 2) | q];
                    if ((t >> 5) == j)
                        logits_out[((size_t)bb * NT + (n - 1)) * NH + t] = lg;
                    float bv = lg; int bi_ = t;
                    #pragma unroll
                    for (int d = 32; d > 0; d >>= 1) {
                        float ov = __shfl_down(bv, d);
                        int   oi = __shfl_down(bi_, d);
                        if (ov > bv || (ov == bv && oi < bi_)) { bv = ov; bi_ = oi; }
                    }
                    if ((t & 63) == 0) {
                        int w = t >> 6;
                        candv[w] = bv; candi[w] = bi_;
                        if (w) __hip_atomic_store(&fc[w], gsc, __ATOMIC_RELEASE, WG);
                    }
                }
            } else if (t < 480) {
                // consume chain d=(c+1)&3's most recent post (3-stage-old: RT hidden)
                int d = (c + 1) & 3;
                int T = (c == 3) ? (n + 1) : n;
                if (T >= 1 && T <= NT) {
                    unsigned long long* hxd = hxp + (size_t)(4 * g + d) * 2 * 256;
                    int guu = (gu32 + 32 + (t - 256)) & 255;
                    unsigned long long* sl = &hxd[((T - 1) & 1) * 256 + guu];
                    unsigned long long pk;
                    for (;;) {
                        pk = __hip_atomic_load(sl, __ATOMIC_RELAXED, AGENT);
                        if ((unsigned)(pk >> 32) == (unsigned)T) break;
                        __builtin_amdgcn_s_sleep(1);
                    }
                    hsp[d][HLAY(guu)] = __uint_as_float((unsigned)pk);
                }
            }

            // ---- mini-sync + step5: sample + gates + post (wave0 only) ----
            if (t < 64) {
                if (n > 0) {
                    // wait for waves 1-3 candidate flags (LDS, monotonic counter)
                    while (__hip_atomic_load(&fc[1], __ATOMIC_ACQUIRE, WG) < gsc ||
                           __hip_atomic_load(&fc[2], __ATOMIC_ACQUIRE, WG) < gsc ||
                           __hip_atomic_load(&fc[3], __ATOMIC_ACQUIRE, WG) < gsc) { }
                    float mv = candv[0]; int mi = candi[0];
                    #pragma unroll
                    for (int w = 1; w < 4; ++w) {
                        float ov = candv[w]; int oi = candi[w];
                        if (ov > mv || (ov == mv && oi < mi)) { mv = ov; mi = oi; }
                    }
                    float v = ((float)mi + 0.5f) * (1.f / 128.f) - 1.f;
                    float av = fabsf(v);
                    float mag = (exp2f(8.f * av) - 1.f) * (1.f / 255.f);
                    float smp = (v >= 0.f) ? mag : -mag;
                    prevc[c] = smp;
                    yaccc[c] = smp + 0.97f * yaccc[c];
                    if (j == 0 && t == 0)
                        wav_out[(size_t)bb * NT + (n - 1)] = yaccc[c];
                }
                if (n < NT && t < 32) {
                    float sr = gr_[c] + wi_r * prevc[c] + bh_r + ghfin[c][t][0];
                    float sz = gz_[c] + wi_z * prevc[c] + bh_z + ghfin[c][t][1];
                    float ni = gn_[c] + wi_n * prevc[c];
                    float nh = bh_n + ghfin[c][t][2];
                    float r = 1.f / (1.f + expf(-sr));
                    float z = 1.f / (1.f + expf(-sz));
                    float nn = tanhf(ni + r * nh);
                    float hn = (1.f - z) * nn + z * hreg[c];
                    hreg[c] = hn;
                    int guu = gu32 + t;
                    hsp[c][HLAY(guu)] = hn;
                    unsigned long long pk =
                        ((unsigned long long)(unsigned)(n + 1) << 32)
                        | (unsigned long long)__float_as_uint(hn);
                    __hip_atomic_store(&hxb[(n & 1) * 256 + guu], pk,
                                       __ATOMIC_RELAXED, AGENT);
                }
            }
            __syncthreads();   // b2
        }

        if (++sif == FS) { sif = 0; ++fr; }
    }
}

// ---------------------------------------------------------------------------
extern "C" void kernel_launch(void* const* d_in, const int* in_sizes, int n_in,
                              void* d_out, int out_size, void* d_ws, size_t ws_size,
                              hipStream_t stream) {
    (void)in_sizes; (void)n_in; (void)out_size; (void)ws_size;

    const float* feat = (const float*)d_in[0];
    const float* c1w  = (const float*)d_in[1];
    const float* c1b  = (const float*)d_in[2];
    const float* c2w  = (const float*)d_in[3];
    const float* c2b  = (const float*)d_in[4];
    const float* f1w  = (const float*)d_in[5];
    const float* f1b  = (const float*)d_in[6];
    const float* f2w  = (const float*)d_in[7];
    const float* f2b  = (const float*)d_in[8];
    const float* gwi  = (const float*)d_in[9];
    const float* gwh  = (const float*)d_in[10];
    const float* gbi  = (const float*)d_in[11];
    const float* gbh  = (const float*)d_in[12];
    const float* outw = (const float*)d_in[13];
    const float* outb = (const float*)d_in[14];

    // workspace layout
    char* ws = (char*)d_ws;
    float* gic = (float*)ws;                                  // 1,572,864 B
    unsigned long long* hxp = (unsigned long long*)(ws + 1572864);  // 32,768 B
    // tag protocol: 0xAAAAAAAA poison never equals any tag (<= 10241),
    // so no memset of hxp is required (d_ws re-poisoned before every launch).

    float* wav    = (float*)d_out;                 // (8,10240,1)
    float* logits = (float*)d_out + NB * NT;       // (8,10240,256)

    frn_kernel<<<dim3(NB * NF), dim3(128), 0, stream>>>(
        feat, c1w, c1b, c2w, c2b, f1w, f1b, f2w, f2b, gwi, gbi, gic);
    ar_kernel<<<dim3(16), dim3(512), 0, stream>>>(
        gic, gwh, outw, gwi, gbh, outb, wav, logits, hxp);
}